// Round 15
// baseline (324.372 us; speedup 1.0000x reference)
//
#include <hip/hip_runtime.h>
#include <hip/hip_bf16.h>
#include <hip/hip_cooperative_groups.h>

namespace cg = cooperative_groups;

#define N_NODES 50000
#define N_EDGES 800000
#define BLK     256
#define NTILES  782            // ceil(50000/64)
#define NB_SCAN 196            // fallback path
// LDS: xp 17408 | rcol 2048 | (colacc 4096 aliases xp)  => 19712 total
#define RC_OFF  17408
#define SMEM_SZ 19712

typedef __attribute__((ext_vector_type(8))) short short8;
typedef __attribute__((ext_vector_type(16))) float f32x16;

struct Params {
  const float* msg; const float* x; const int* ei; const float* ea;
  const float* Wl; const float* bl; const float* Wr; const float* br;
  const float* We; const float* att; const float* bias;
  const float* Wfc; const float* bfc;
  float4* rec; float* nodeF;
  short* bfrag_hi; short* bfrag_lo;    // me in MFMA B-fragment order
  int* cnt; float* colsum; int* offs; int* cursor; int* bsum;
  float* dout;
};

// ---- build split-bf16 A fragments (h computed on the fly from nodeF) ----
__device__ __forceinline__ void build_A(const Params& P, int row, int lhalf,
                                        short8* a_hi, short8* a_lo)
{
  float c0a = 0.f, c0b = 0.f, c0d = 0.f, c1a = 0.f, c1b = 0.f, c1d = 0.f;
  bool live = row < N_NODES;
  if (live) {
    const float* nf = P.nodeF + (size_t)row * 8;
    float D0 = nf[0], A00 = nf[1], A10 = nf[2];
    float D1 = nf[3], A01 = nf[4], A11 = nf[5];
    float r0 = 1.0f / (D0 + 1e-16f), r1 = 1.0f / (D1 + 1e-16f);
    c0a = A00 * r0; c0b = A10 * r0; c0d = D0 * r0;
    c1a = A01 * r1; c1b = A11 * r1; c1d = D1 * r1;
  }
  #pragma unroll
  for (int ks = 0; ks < 8; ++ks) {
    int k0 = ks * 16 + lhalf * 8;
    float ca = (ks < 4) ? c0a : c1a;
    float cbv = (ks < 4) ? c0b : c1b;
    float cd = (ks < 4) ? c0d : c1d;
    float wA[8], wB[8], wC[8], wD[8];
    *(float4*)&wA[0] = *(const float4*)(P.Wl + k0);
    *(float4*)&wA[4] = *(const float4*)(P.Wl + k0 + 4);
    *(float4*)&wB[0] = *(const float4*)(P.Wl + 128 + k0);
    *(float4*)&wB[4] = *(const float4*)(P.Wl + 128 + k0 + 4);
    *(float4*)&wC[0] = *(const float4*)(P.bl + k0);
    *(float4*)&wC[4] = *(const float4*)(P.bl + k0 + 4);
    *(float4*)&wD[0] = *(const float4*)(P.bias + k0);
    *(float4*)&wD[4] = *(const float4*)(P.bias + k0 + 4);
    short8 hi8, lo8;
    #pragma unroll
    for (int j = 0; j < 8; ++j) {
      float v = ca * wA[j] + cbv * wB[j] + cd * wC[j] + wD[j];
      v = (live && v > 0.f) ? v : 0.f;
      __hip_bfloat16 hb = __float2bfloat16(v);
      float rem = v - __bfloat162float(hb);
      __hip_bfloat16 lb = __float2bfloat16(rem);
      short hs, ls;
      __builtin_memcpy(&hs, &hb, 2);
      __builtin_memcpy(&ls, &lb, 2);
      hi8[j] = hs; lo8[j] = ls;
    }
    a_hi[ks] = hi8; a_lo[ks] = lo8;
  }
}

// ---- MFMA for one 64x64 tile-column pair: B direct from L2 (fragment order)
// chunk index = colgroup*512 + ks*64 + l : lane l reads its 16B fragment,
// consecutive lanes = consecutive chunks -> 1KB coalesced, L2-resident.
__device__ __forceinline__ f32x16 mfma_block(const Params& P, int colgroup, int l,
                                             const short8* a_hi, const short8* a_lo)
{
  const short8* BH = (const short8*)P.bfrag_hi + (size_t)colgroup * 512 + l;
  const short8* BL = (const short8*)P.bfrag_lo + (size_t)colgroup * 512 + l;
  f32x16 acc = {0.f};
  #pragma unroll
  for (int ks = 0; ks < 8; ++ks) {
    short8 bh = BH[ks * 64];
    short8 blo = BL[ks * 64];
    acc = __builtin_amdgcn_mfma_f32_32x32x16_bf16(a_hi[ks], bh, acc, 0, 0, 0);
    acc = __builtin_amdgcn_mfma_f32_32x32x16_bf16(a_lo[ks], bh, acc, 0, 0, 0);
    acc = __builtin_amdgcn_mfma_f32_32x32x16_bf16(a_hi[ks], blo, acc, 0, 0, 0);
  }
  return acc;
}

// ---- PASS 0: colsum; zero barriers inside tile loop ----
__device__ __forceinline__ void mfma_colsum_tiles(const Params& P, int b, int G,
                                                  char* SMEM)
{
  float* colacc = (float*)SMEM;          // 1024 floats (aliases xp region)
  const int tid = threadIdx.x;
  const int l = tid & 63, w = tid >> 6;
  const int rt = w >> 1, ct = w & 1;
  const int lrow = l & 31, lhalf = l >> 5;

  #pragma unroll
  for (int q = 0; q < 4; ++q) colacc[q * 256 + tid] = 0.f;
  __syncthreads();

  for (int tile = b; tile < NTILES; tile += G) {
    int m0 = tile * 64;
    short8 a_hi[8], a_lo[8];
    build_A(P, m0 + rt * 32 + lrow, lhalf, a_hi, a_lo);
    #pragma unroll 2
    for (int cb = 0; cb < 8; ++cb) {
      f32x16 acc = mfma_block(P, cb * 2 + ct, l, a_hi, a_lo);
      float csum = 0.f;
      #pragma unroll
      for (int i = 0; i < 16; ++i) {
        int grow = m0 + rt * 32 + (i & 3) + 8 * (i >> 2) + 4 * lhalf;
        csum += (grow < N_NODES) ? __expf(acc[i]) : 0.f;
      }
      csum += __shfl_xor(csum, 32);
      if (l < 32) colacc[rt * 512 + cb * 64 + ct * 32 + l] += csum;
    }
  }
  __syncthreads();
  atomicAdd(&P.colsum[tid], colacc[tid] + colacc[512 + tid]);
  atomicAdd(&P.colsum[tid + 256], colacc[256 + tid] + colacc[768 + tid]);
}

// ---- PASS 1: normalize + store; 2 barriers per cb (xp transpose) ----
__device__ __forceinline__ void mfma_store_tiles(const Params& P, int b, int G,
                                                 char* SMEM)
{
  float* xp = (float*)SMEM;              // 64*68 floats
  float* rcol = (float*)(SMEM + RC_OFF); // 512 floats
  const int tid = threadIdx.x;
  const int l = tid & 63, w = tid >> 6;
  const int rt = w >> 1, ct = w & 1;
  const int lrow = l & 31, lhalf = l >> 5;

  rcol[tid] = 1.0f / P.colsum[tid];
  rcol[tid + 256] = 1.0f / P.colsum[tid + 256];
  __syncthreads();

  for (int tile = b; tile < NTILES; tile += G) {
    int m0 = tile * 64;
    short8 a_hi[8], a_lo[8];
    build_A(P, m0 + rt * 32 + lrow, lhalf, a_hi, a_lo);
    for (int cb = 0; cb < 8; ++cb) {
      f32x16 acc = mfma_block(P, cb * 2 + ct, l, a_hi, a_lo);
      #pragma unroll
      for (int i = 0; i < 16; ++i) {
        int rl = rt * 32 + (i & 3) + 8 * (i >> 2) + 4 * lhalf;
        xp[rl * 68 + ct * 32 + lrow] = __expf(acc[i]);
      }
      __syncthreads();         // xp ready
      #pragma unroll
      for (int q = 0; q < 4; ++q) {
        int fid = q * 256 + tid;
        int rl = fid >> 4, c4 = fid & 15;
        int grow = m0 + rl;
        float4 v = *(float4*)&xp[rl * 68 + c4 * 4];
        float4 s = *(const float4*)&rcol[cb * 64 + c4 * 4];
        v.x *= s.x; v.y *= s.y; v.z *= s.z; v.w *= s.w;
        if (grow < N_NODES) {
          *(float4*)&P.dout[(size_t)grow * 1024 + cb * 64 + c4 * 4] = v;
          *(float4*)&P.dout[(size_t)grow * 1024 + 512 + cb * 64 + c4 * 4] = v;
        }
      }
      __syncthreads();         // WAR: xp reads done before next cb overwrite
    }
  }
}

// ================= cooperative mega-kernel =================
__global__ __launch_bounds__(BLK, 2) void k_all(Params P)
{
  cg::grid_group gg = cg::this_grid();
  __shared__ __align__(16) char SMEM[SMEM_SZ];
  const int b = blockIdx.x, t = threadIdx.x;
  const int G = gridDim.x;

  // P0: fc -> write me in B-fragment order (blocks 0-255) + zero (256-453)
  if (b < 256) {
    float* mrow = (float*)SMEM;
    int r = 2 * b + (t >> 7);            // output col index 0..511
    int k = t & 127;
    mrow[t] = P.msg[r * 128 + k];
    __syncthreads();
    int base = (t >> 7) * 128;
    float acc = P.bfc[k];
    #pragma unroll 8
    for (int kk = 0; kk < 128; ++kk)
      acc = fmaf(mrow[base + kk], P.Wfc[kk * 128 + k], acc);
    __hip_bfloat16 hb = __float2bfloat16(acc);
    float rem = acc - __bfloat162float(hb);
    __hip_bfloat16 lb = __float2bfloat16(rem);
    short hs, ls;
    __builtin_memcpy(&hs, &hb, 2);
    __builtin_memcpy(&ls, &lb, 2);
    // fragment address: chunk = ((r>>5)*8 + (k>>4))*64 + ((k>>3)&1)*32 + (r&31)
    size_t idx = ((size_t)((r >> 5) * 8 + (k >> 4)) * 64
                  + ((k >> 3) & 1) * 32 + (r & 31)) * 8 + (k & 7);
    P.bfrag_hi[idx] = hs;
    P.bfrag_lo[idx] = ls;
  } else if (b < 454) {
    int i = (b - 256) * 256 + t;
    if (i < N_NODES + 512) P.cnt[i] = 0;   // cnt + adjacent colsum
  }
  gg.sync();

  // P1: histogram of dst
  for (int e = b * BLK + t; e < N_EDGES; e += G * BLK)
    atomicAdd(&P.cnt[P.ei[N_EDGES + e]], 1);
  gg.sync();

  const int CH = (N_NODES + G - 1) / G;    // 49/66/98 for G=1024/768/512

  // P2: per-chunk local exclusive scan (scan width 128, CH <= 128)
  {
    int* sh = (int*)SMEM;
    int base = b * CH;
    if (t < 128) sh[t] = 0;
    __syncthreads();
    int v = 0;
    if (t < 128 && t < CH && base + t < N_NODES) { v = P.cnt[base + t]; sh[t] = v; }
    __syncthreads();
    #pragma unroll
    for (int off = 1; off < 128; off <<= 1) {
      int u = (t < 128 && t >= off) ? sh[t - off] : 0;
      __syncthreads();
      if (t < 128) sh[t] += u;
      __syncthreads();
    }
    if (t < 128 && t < CH && base + t < N_NODES) P.offs[base + t] = sh[t] - v;
    if (t == 0) P.bsum[b] = sh[127];
  }
  gg.sync();

  // P3: every block scans the G block-sums; add-back + cursor init
  {
    int* eb = (int*)SMEM;                // G exclusive values (<=1024)
    int* s3 = eb + 1024;                 // 256 partials
    const int nb = G >> 8;               // 2/3/4
    int xv[4];
    int ssum = 0;
    for (int j = 0; j < nb; ++j) { xv[j] = P.bsum[nb * t + j]; ssum += xv[j]; }
    s3[t] = ssum;
    __syncthreads();
    #pragma unroll
    for (int off = 1; off < 256; off <<= 1) {
      int u = (t >= off) ? s3[t - off] : 0;
      __syncthreads();
      s3[t] += u;
      __syncthreads();
    }
    int p = t ? s3[t - 1] : 0;
    for (int j = 0; j < nb; ++j) { eb[nb * t + j] = p; p += xv[j]; }
    __syncthreads();
    int pb = eb[b];
    int base = b * CH;
    if (t < CH && base + t < N_NODES) {
      int o = P.offs[base + t] + pb;
      P.offs[base + t] = o;
      P.cursor[base + t] = o;
    }
    if (b == 0 && t == 0) P.offs[N_NODES] = N_EDGES;
  }
  gg.sync();

  // P4: fused score + scatter
  for (int e = b * BLK + t; e < N_EDGES; e += G * BLK) {
    int s = P.ei[e], d = P.ei[N_EDGES + e];
    float x0s = P.x[2*s], x1s = P.x[2*s+1];
    float x0d = P.x[2*d], x1d = P.x[2*d+1];
    float av = P.ea[e];
    float s0 = 0.f, s1 = 0.f;
    #pragma unroll 8
    for (int k = 0; k < 64; ++k) {
      float m = P.bl[k] + P.br[k];
      m = fmaf(x0s, P.Wl[k], m);
      m = fmaf(x1s, P.Wl[128+k], m);
      m = fmaf(x0d, P.Wr[k], m);
      m = fmaf(x1d, P.Wr[128+k], m);
      m = fmaf(av, P.We[k], m);
      float lk = m > 0.f ? m : 0.2f * m;
      s0 = fmaf(lk, P.att[k], s0);
    }
    #pragma unroll 8
    for (int k = 64; k < 128; ++k) {
      float m = P.bl[k] + P.br[k];
      m = fmaf(x0s, P.Wl[k], m);
      m = fmaf(x1s, P.Wl[128+k], m);
      m = fmaf(x0d, P.Wr[k], m);
      m = fmaf(x1d, P.Wr[128+k], m);
      m = fmaf(av, P.We[k], m);
      float lk = m > 0.f ? m : 0.2f * m;
      s1 = fmaf(lk, P.att[k], s1);
    }
    int pos = atomicAdd(&P.cursor[d], 1);
    P.rec[pos] = make_float4(s0, s1, x0s, x1s);
  }
  gg.sync();

  // P5: per-node gather reduction
  {
    int n = b * BLK + t;
    if (n < N_NODES) {
      int a = P.offs[n], bb = P.offs[n + 1];
      float D0 = 0.f, A00 = 0.f, A10 = 0.f;
      float D1 = 0.f, A01 = 0.f, A11 = 0.f;
      for (int i = a; i < bb; ++i) {
        float4 r = P.rec[i];
        float e0 = __expf(r.x);
        float e1 = __expf(r.y);
        D0 += e0; A00 += e0 * r.z; A10 += e0 * r.w;
        D1 += e1; A01 += e1 * r.z; A11 += e1 * r.w;
      }
      float* nf = P.nodeF + (size_t)n * 8;
      nf[0] = D0; nf[1] = A00; nf[2] = A10;
      nf[3] = D1; nf[4] = A01; nf[5] = A11;
    }
  }
  gg.sync();

  // P6: MFMA colsum pass (no LDS-B, no in-loop barriers)
  mfma_colsum_tiles(P, b, G, SMEM);
  gg.sync();

  // P7: MFMA normalize + store pass
  mfma_store_tiles(P, b, G, SMEM);
}

// ================= fallback multi-kernel path =================
__global__ __launch_bounds__(256) void k_zero(int* __restrict__ buf)
{
  int i = blockIdx.x * 256 + threadIdx.x;
  if (i < N_NODES + 512) buf[i] = 0;
}

__global__ __launch_bounds__(256) void k_hist(
    const int* __restrict__ ei, int* __restrict__ cnt)
{
  int e = blockIdx.x * 256 + threadIdx.x;
  if (e >= N_EDGES) return;
  atomicAdd(&cnt[ei[N_EDGES + e]], 1);
}

__global__ __launch_bounds__(256) void k_scan1(
    const int* __restrict__ cnt, int* __restrict__ offs, int* __restrict__ bsum)
{
  __shared__ int sh[256];
  int b = blockIdx.x, t = threadIdx.x;
  int i = b * 256 + t;
  int v = (i < N_NODES) ? cnt[i] : 0;
  sh[t] = v;
  __syncthreads();
  #pragma unroll
  for (int off = 1; off < 256; off <<= 1) {
    int u = (t >= off) ? sh[t - off] : 0;
    __syncthreads();
    sh[t] += u;
    __syncthreads();
  }
  if (i < N_NODES) offs[i] = sh[t] - v;
  if (t == 255) bsum[b] = sh[255];
}

__global__ __launch_bounds__(256) void k_scan2(int* __restrict__ bsum)
{
  __shared__ int sh[256];
  int t = threadIdx.x;
  int v = (t < NB_SCAN) ? bsum[t] : 0;
  sh[t] = v;
  __syncthreads();
  #pragma unroll
  for (int off = 1; off < 256; off <<= 1) {
    int u = (t >= off) ? sh[t - off] : 0;
    __syncthreads();
    sh[t] += u;
    __syncthreads();
  }
  if (t < NB_SCAN) bsum[t] = sh[t] - v;
}

__global__ __launch_bounds__(256) void k_scan3(
    int* __restrict__ offs, const int* __restrict__ bsum, int* __restrict__ cursor)
{
  int b = blockIdx.x, t = threadIdx.x;
  int i = b * 256 + t;
  if (i < N_NODES) {
    int o = offs[i] + bsum[b];
    offs[i] = o;
    cursor[i] = o;
  }
  if (b == 0 && t == 0) offs[N_NODES] = N_EDGES;
}

__global__ __launch_bounds__(256) void k_scatter(Params P)
{
  int e = blockIdx.x * 256 + threadIdx.x;
  if (e >= N_EDGES) return;
  int s = P.ei[e], d = P.ei[N_EDGES + e];
  float x0s = P.x[2*s], x1s = P.x[2*s+1];
  float x0d = P.x[2*d], x1d = P.x[2*d+1];
  float av = P.ea[e];
  float s0 = 0.f, s1 = 0.f;
  #pragma unroll 8
  for (int k = 0; k < 64; ++k) {
    float m = P.bl[k] + P.br[k];
    m = fmaf(x0s, P.Wl[k], m);
    m = fmaf(x1s, P.Wl[128+k], m);
    m = fmaf(x0d, P.Wr[k], m);
    m = fmaf(x1d, P.Wr[128+k], m);
    m = fmaf(av, P.We[k], m);
    float lk = m > 0.f ? m : 0.2f * m;
    s0 = fmaf(lk, P.att[k], s0);
  }
  #pragma unroll 8
  for (int k = 64; k < 128; ++k) {
    float m = P.bl[k] + P.br[k];
    m = fmaf(x0s, P.Wl[k], m);
    m = fmaf(x1s, P.Wl[128+k], m);
    m = fmaf(x0d, P.Wr[k], m);
    m = fmaf(x1d, P.Wr[128+k], m);
    m = fmaf(av, P.We[k], m);
    float lk = m > 0.f ? m : 0.2f * m;
    s1 = fmaf(lk, P.att[k], s1);
  }
  int pos = atomicAdd(&P.cursor[d], 1);
  P.rec[pos] = make_float4(s0, s1, x0s, x1s);
}

__global__ __launch_bounds__(256) void k_gather(Params P)
{
  int n = blockIdx.x * 256 + threadIdx.x;
  if (n >= N_NODES) return;
  int a = P.offs[n], b = P.offs[n + 1];
  float D0 = 0.f, A00 = 0.f, A10 = 0.f;
  float D1 = 0.f, A01 = 0.f, A11 = 0.f;
  for (int i = a; i < b; ++i) {
    float4 r = P.rec[i];
    float e0 = __expf(r.x);
    float e1 = __expf(r.y);
    D0 += e0; A00 += e0 * r.z; A10 += e0 * r.w;
    D1 += e1; A01 += e1 * r.z; A11 += e1 * r.w;
  }
  float* nf = P.nodeF + (size_t)n * 8;
  nf[0] = D0; nf[1] = A00; nf[2] = A10;
  nf[3] = D1; nf[4] = A01; nf[5] = A11;
}

__global__ __launch_bounds__(128) void k_fc(Params P)
{
  int r = blockIdx.x, k = threadIdx.x;
  __shared__ float mrow[128];
  mrow[k] = P.msg[r*128 + k];
  __syncthreads();
  float acc = P.bfc[k];
  #pragma unroll 8
  for (int t = 0; t < 128; ++t) acc = fmaf(mrow[t], P.Wfc[t*128 + k], acc);
  __hip_bfloat16 hb = __float2bfloat16(acc);
  float rem = acc - __bfloat162float(hb);
  __hip_bfloat16 lb = __float2bfloat16(rem);
  short hs, ls;
  __builtin_memcpy(&hs, &hb, 2);
  __builtin_memcpy(&ls, &lb, 2);
  size_t idx = ((size_t)((r >> 5) * 8 + (k >> 4)) * 64
                + ((k >> 3) & 1) * 32 + (r & 31)) * 8 + (k & 7);
  P.bfrag_hi[idx] = hs;
  P.bfrag_lo[idx] = ls;
}

template<int PASS>
__global__ __launch_bounds__(256, 2) void k_mfma(Params P)
{
  __shared__ __align__(16) char SMEM[SMEM_SZ];
  if (PASS == 0) mfma_colsum_tiles(P, blockIdx.x, gridDim.x, SMEM);
  else           mfma_store_tiles(P, blockIdx.x, gridDim.x, SMEM);
}

extern "C" void kernel_launch(void* const* d_in, const int* in_sizes, int n_in,
                              void* d_out, int out_size, void* d_ws, size_t ws_size,
                              hipStream_t stream)
{
  Params P;
  P.msg = (const float*)d_in[0];
  P.x   = (const float*)d_in[1];
  P.ei  = (const int*)d_in[2];
  P.ea  = (const float*)d_in[3];
  // conv1 params (d_in[4..10]) are dead code in the reference
  P.Wl   = (const float*)d_in[11];
  P.bl   = (const float*)d_in[12];
  P.Wr   = (const float*)d_in[13];
  P.br   = (const float*)d_in[14];
  P.We   = (const float*)d_in[15];
  P.att  = (const float*)d_in[16];
  P.bias = (const float*)d_in[17];
  P.Wfc  = (const float*)d_in[18];
  P.bfc  = (const float*)d_in[19];

  char* p = (char*)d_ws;
  P.rec = (float4*)p;                    p += (size_t)N_EDGES * 16;
  P.nodeF = (float*)p;                   p += (size_t)N_NODES * 8 * 4;
  P.bfrag_hi = (short*)p;                p += 512 * 128 * 2;
  P.bfrag_lo = (short*)p;                p += 512 * 128 * 2;
  P.cnt = (int*)p;                       p += (size_t)N_NODES * 4;   // colsum adjacent
  P.colsum = (float*)p;                  p += 512 * 4;
  P.offs = (int*)p;                      p += (size_t)(N_NODES + 1) * 4;
  P.cursor = (int*)p;                    p += (size_t)N_NODES * 4;
  P.bsum = (int*)p;                      p += 1024 * 4;
  P.dout = (float*)d_out;

  // occupancy-cascaded cooperative launch, multi-kernel fallback
  int maxBlk = 0;
  hipError_t qerr = hipOccupancyMaxActiveBlocksPerMultiprocessor(&maxBlk, k_all, BLK, 0);
  if (qerr == hipSuccess && maxBlk >= 2) {
    int g = (maxBlk >= 4) ? 1024 : (maxBlk >= 3 ? 768 : 512);
    void* args[] = { &P };
    hipError_t lerr = hipLaunchCooperativeKernel((void*)k_all, dim3(g), dim3(BLK),
                                                 args, 0, stream);
    if (lerr == hipSuccess) return;
  }

  // ---- fallback: multi-kernel pipeline ----
  k_zero<<<(N_NODES + 512 + 255) / 256, 256, 0, stream>>>(P.cnt);
  k_hist<<<(N_EDGES + 255) / 256, 256, 0, stream>>>(P.ei, P.cnt);
  k_scan1<<<NB_SCAN, 256, 0, stream>>>(P.cnt, P.offs, P.bsum);
  k_scan2<<<1, 256, 0, stream>>>(P.bsum);
  k_scan3<<<NB_SCAN, 256, 0, stream>>>(P.offs, P.bsum, P.cursor);
  k_scatter<<<(N_EDGES + 255) / 256, 256, 0, stream>>>(P);
  k_gather<<<(N_NODES + 255) / 256, 256, 0, stream>>>(P);
  k_fc<<<512, 128, 0, stream>>>(P);
  k_mfma<0><<<NTILES, 256, 0, stream>>>(P);
  k_mfma<1><<<NTILES, 256, 0, stream>>>(P);
}